// Round 6
// baseline (50.012 us; speedup 1.0000x reference)
//
#include <hip/hip_runtime.h>
#include <hip/hip_bf16.h>

// Problem constants (from reference): B=32, N=2048, M=16, K=32, H=in_sizes[2]
constexpr int Bc = 32;
constexpr int Nc = 2048;
constexpr int Mc = 16;
constexpr int Kc = 32;
constexpr int ROWc = Mc + 1;       // 17 floats per dgm row
constexpr float EPSc = 1e-7f;

// ---------------------------------------------------------------------------
// Kernel A: one block per (b,k), 256 threads, 1024 blocks (4/CU co-resident).
// Double-buffered LDS staging: chunk c+1's global loads are issued into
// registers before the mid-barrier and overlap chunk c's compute; ds_write
// to the alternate buffer afterwards. Removes 8 serial global-load
// latencies from the per-block critical path.
// ---------------------------------------------------------------------------
__global__ __launch_bounds__(256, 4) void k_fused(const float* __restrict__ dgm,
                                                  const float* __restrict__ theta,
                                                  const float* __restrict__ class_w,
                                                  float* __restrict__ T,
                                                  int H) {
    __shared__ float lds[2][256 * ROWc];   // 2 x 17408 B
    __shared__ int   wmin[4];
    __shared__ float red[4][Mc];

    int bk  = blockIdx.x;
    int b   = bk >> 5;                  // K = 32
    int k   = bk & 31;
    int tid = threadIdx.x;
    int wid = tid >> 6;

    float th[Mc];
#pragma unroll
    for (int m = 0; m < Mc; ++m) th[m] = theta[k * Mc + m];

    float acc[Mc];
#pragma unroll
    for (int m = 0; m < Mc; ++m) acc[m] = 0.0f;

    const float* base = dgm + (size_t)b * Nc * ROWc;

    // stage chunk 0 into lds[0] (1088 float4, fully coalesced)
    {
        const float4* s4 = (const float4*)base;
        float4* l4 = (float4*)lds[0];
#pragma unroll
        for (int j = 0; j < 4; ++j) l4[tid + j * 256] = s4[tid + j * 256];
        if (tid < 64) l4[1024 + tid] = s4[1024 + tid];
    }
    __syncthreads();

    int fzb = 0x7FFFFFFF;
    int cur = 0;

    for (int c0 = 0; c0 < Nc; c0 += 256) {
        // ---- own row from lds[cur] (stride-17: 2-way conflict = free) ----
        float r[ROWc];
#pragma unroll
        for (int j = 0; j < ROWc; ++j) r[j] = lds[cur][tid * ROWc + j];

        // ---- chunk-local first-zero-row partial (per-wave) ----
        bool nz = false;
#pragma unroll
        for (int j = 0; j < ROWc; ++j) nz = nz || (r[j] != 0.0f);
        int lm = nz ? 0x7FFFFFFF : (c0 + tid);
#pragma unroll
        for (int mask = 32; mask >= 1; mask >>= 1)
            lm = min(lm, __shfl_xor(lm, mask));
        if ((tid & 63) == 0) wmin[wid] = lm;

        // ---- prefetch next chunk into registers (overlaps compute) ----
        // safe to use stale fzb: it only shrinks, and if c0+256 >= fzb_prev
        // then the updated fzb also triggers the break below.
        bool want = (c0 + 256 < Nc) && (c0 + 256 < fzb);
        float4 pf[4], pfx;
        if (want) {
            const float4* s4 = (const float4*)(base + (size_t)(c0 + 256) * ROWc);
#pragma unroll
            for (int j = 0; j < 4; ++j) pf[j] = s4[tid + j * 256];
            if (tid < 64) pfx = s4[1024 + tid];
        }

        __syncthreads();
        fzb = min(fzb, min(min(wmin[0], wmin[1]), min(wmin[2], wmin[3])));

        // ---- accumulate valid rows (registers only) ----
        int n = c0 + tid;
        if (n < fzb) {
            int h = (int)r[0];              // trunc == astype(int32)
            h = max(0, min(h, H - 1));
            float wv = class_w[h];

            float z[Mc];
            float zn2 = 0.0f;
#pragma unroll
            for (int m = 0; m < Mc; ++m) {
                z[m] = r[1 + m] * th[m];
                zn2  = fmaf(z[m], z[m], zn2);
            }
            float d   = 1.0f / (1.0f + sqrtf(1.0f + zn2));
            float xn2 = zn2 * d * d;        // ||x||^2 = d^2 ||z||^2
            float xn  = sqrtf(xn2);
            float u   = fminf(xn, 1.0f - EPSc);
            float at  = 0.5f * __logf((1.0f + u) / (1.0f - u));  // atanh
            float coef = at / fmaxf(xn, EPSc) * d * wv;          // 0 if wv==0
#pragma unroll
            for (int m = 0; m < Mc; ++m) acc[m] = fmaf(coef, z[m], acc[m]);
        }

        // ---- commit prefetch to the other buffer ----
        if (want) {
            float4* l4 = (float4*)lds[cur ^ 1];
#pragma unroll
            for (int j = 0; j < 4; ++j) l4[tid + j * 256] = pf[j];
            if (tid < 64) l4[1024 + tid] = pfx;
            cur ^= 1;
        }

        if (c0 + 256 >= fzb) break;         // all later rows invalid
        __syncthreads();                    // prefetch visible for next iter
    }

    // ---- block reduce: wave-64 shfl, then LDS across the 4 waves ----
#pragma unroll
    for (int m = 0; m < Mc; ++m) {
#pragma unroll
        for (int mask = 32; mask >= 1; mask >>= 1)
            acc[m] += __shfl_xor(acc[m], mask);
    }
    if ((tid & 63) == 0) {
#pragma unroll
        for (int m = 0; m < Mc; ++m) red[wid][m] = acc[m];
    }
    __syncthreads();
    if (tid < Mc) {
        int m = tid;
        T[(size_t)bk * Mc + m] = red[0][m] + red[1][m] + red[2][m] + red[3][m];
    }
}

// ---------------------------------------------------------------------------
// Kernel B: S = cumsum over flattened (B*K, M) rows of T, then
//           yd = 2*xd/(1-||xd||^2), xd = tanh(||S||)*S/max(||S||,eps).
// Single block, 1024 threads. thread = (m = tid&15, seg = tid>>4).
// ---------------------------------------------------------------------------
__global__ __launch_bounds__(1024) void k_scan(float* __restrict__ T) {
    __shared__ float buf[2][64][Mc];

    int tid = threadIdx.x;
    int m   = tid & 15;
    int seg = tid >> 4;            // 0..63, 16 rows each -> 1024 rows

    float p[16];
    float run = 0.0f;
#pragma unroll
    for (int j = 0; j < 16; ++j) {
        run += T[(size_t)(seg * 16 + j) * Mc + m];
        p[j] = run;
    }

    buf[0][seg][m] = run;
    __syncthreads();
    int src = 0;
#pragma unroll
    for (int d = 1; d < 64; d <<= 1) {
        float v = buf[src][seg][m];
        if (seg >= d) v += buf[src][seg - d][m];
        buf[src ^ 1][seg][m] = v;
        __syncthreads();
        src ^= 1;
    }
    float off = (seg > 0) ? buf[src][seg - 1][m] : 0.0f;

#pragma unroll
    for (int j = 0; j < 16; ++j) {
        float S = off + p[j];
        float sn2 = S * S;
        sn2 += __shfl_xor(sn2, 1);
        sn2 += __shfl_xor(sn2, 2);
        sn2 += __shfl_xor(sn2, 4);
        sn2 += __shfl_xor(sn2, 8);
        float sn = sqrtf(sn2);
        // tanh(sn) = 1 - 2/(e^{2 sn}+1)
        float e  = __expf(2.0f * sn);
        float t  = 1.0f - 2.0f / (e + 1.0f);
        float c  = t / fmaxf(sn, EPSc);
        float sx2 = c * c * sn2;               // == sum(xd^2)
        float yd = 2.0f * c * S / (1.0f - sx2);
        T[(size_t)(seg * 16 + j) * Mc + m] = yd;
    }
}

// ---------------------------------------------------------------------------
extern "C" void kernel_launch(void* const* d_in, const int* in_sizes, int n_in,
                              void* d_out, int out_size, void* d_ws, size_t ws_size,
                              hipStream_t stream) {
    const float* dgm     = (const float*)d_in[0];   // (B, N, 17)
    const float* theta   = (const float*)d_in[1];   // (K, M)
    const float* class_w = (const float*)d_in[2];   // (H,)
    int H = in_sizes[2];

    float* out = (float*)d_out;                     // T, then yd in place

    k_fused<<<Bc * Kc, 256, 0, stream>>>(dgm, theta, class_w, out, H);
    k_scan<<<1, 1024, 0, stream>>>(out);
}